// Round 6
// baseline (454.058 us; speedup 1.0000x reference)
//
#include <hip/hip_runtime.h>
#include <hip/hip_bf16.h>

typedef __attribute__((ext_vector_type(8))) short bf16x8;
typedef __attribute__((ext_vector_type(4))) float f32x4;
typedef __attribute__((ext_vector_type(4))) unsigned int uint4v;

namespace {

constexpr int kT = 16;
constexpr int kC = 256;
constexpr int kHW = 1024;

__device__ __forceinline__ unsigned short f2bf(float f) {
  unsigned int x;
  __builtin_memcpy(&x, &f, 4);
  x += 0x7fff + ((x >> 16) & 1);  // round-to-nearest-even
  return (unsigned short)(x >> 16);
}
__device__ __forceinline__ unsigned int pack2(float a, float b) {
  return (unsigned int)f2bf(a) | ((unsigned int)f2bf(b) << 16);
}
__device__ __forceinline__ bf16x8 ntload8(const unsigned short* p) {
  uint4v v = __builtin_nontemporal_load((const uint4v*)p);
  bf16x8 r;
  __builtin_memcpy(&r, &v, 16);
  return r;
}
__device__ __forceinline__ f32x4 ntload4f(const float* p) {
  return __builtin_nontemporal_load((const f32x4*)p);
}

// ============================ prep kernel (r4-proven) ============================
__global__ __launch_bounds__(256) void prep(const float* __restrict__ x,
                                            const float* __restrict__ wqkv,
                                            const float* __restrict__ wout,
                                            unsigned short* __restrict__ xT,
                                            unsigned short* __restrict__ wAll) {
  __shared__ unsigned short ts[64 * 72];
  const int bx = blockIdx.x;
  const int tid = threadIdx.x;
  if (bx < 4096) {
    const int cc = bx & 3, hc = (bx >> 2) & 15, t = (bx >> 6) & 15, b = bx >> 10;
    const int c0 = cc * 64, hw0 = hc * 64;
    {
      const int ci = tid >> 2, j = tid & 3;
      const float* xrow = x + (((size_t)(b * 16 + t) * 256 + c0 + ci) * 1024) + hw0;
#pragma unroll
      for (int u = 0; u < 4; ++u) {
        const int chunk = j + u * 4;
        const f32x4 v = ntload4f(xrow + chunk * 4);
        const int hwl = chunk * 4;
        ts[(hwl + 0) * 72 + ci] = f2bf(v.x);
        ts[(hwl + 1) * 72 + ci] = f2bf(v.y);
        ts[(hwl + 2) * 72 + ci] = f2bf(v.z);
        ts[(hwl + 3) * 72 + ci] = f2bf(v.w);
      }
    }
    __syncthreads();
    {
      const int hwp = tid >> 2, jp = tid & 3;
      const uint4 a = *(const uint4*)&ts[hwp * 72 + jp * 16];
      const uint4 bq = *(const uint4*)&ts[hwp * 72 + jp * 16 + 8];
      unsigned short* dst =
          xT + ((size_t)((b * 1024 + hw0 + hwp) * 16 + t) * 256) + c0 + jp * 16;
      *(uint4*)dst = a;
      *(uint4*)(dst + 8) = bq;
    }
  } else {
    const int g = bx - 4096;            // 0..31
    const int row_l = tid >> 3;
    const int seg = tid & 7;
    const float* src;
    int srow;
    if (g < 24) { src = wqkv; srow = (g % 3) * 256 + (g / 3) * 32 + row_l; }
    else        { src = wout; srow = (g - 24) * 32 + row_l; }
    const float* s = src + (size_t)srow * 256 + seg * 32;
    unsigned short* d = wAll + ((size_t)(g * 32 + row_l)) * 256 + seg * 32;
#pragma unroll
    for (int u = 0; u < 8; ++u) {
      const float4 v = *(const float4*)(s + u * 4);
      uint2 p;
      p.x = pack2(v.x, v.y);
      p.y = pack2(v.z, v.w);
      *(uint2*)(d + u * 4) = p;
    }
  }
}

// ============================ main kernel ============================
// 512 thr = 8 waves; wave = 1 hw site (16x16x32 MFMA); block = 8 consecutive
// hw; grid 512 = 2 blocks/CU = 4 waves/SIMD. wqkv dbuf-staged in LDS; xT
// loads non-temporal so wAll stays L2-resident.
constexpr int kWBStride = 264;                 // 256 + 8 pad
constexpr int kWBTile = 32 * kWBStride;        // 8448 elems
constexpr int kWB = 2 * kWBTile;               // 16896 elems
constexpr int kSite = 1824;                    // q640(s40)|k640(s40,P s24)|vt512(s16)|pad
constexpr int kSmem = kWB + 8 * kSite;         // 31488 elems = 62976 B
static_assert(kSmem * 2 <= 65536, "LDS budget");

struct Acc2 { f32x4 a0, a1; };

__global__ __launch_bounds__(512, 4) void attn_main(
    const unsigned short* __restrict__ xT,    // (4,1024,16,256) bf16
    const float* __restrict__ rel,            // (8,16,16) fp32
    const unsigned short* __restrict__ wAll,  // (1024,256) bf16 reordered
    const float* __restrict__ bqkv,           // (768,) fp32
    const float* __restrict__ bout,           // (256,) fp32
    float* __restrict__ out) {                // (4,16,256,32,32) fp32
  __shared__ __align__(16) unsigned short smem[kSmem];
  const int tid = threadIdx.x;
  const int lane = tid & 63;
  const int wave = tid >> 6;  // 0..7 = site index in block
  const int quad = lane >> 4;
  const int lrow = lane & 15;
  const int b = blockIdx.x >> 7;
  const int hw0 = (blockIdx.x & 127) * 8;
  const int site = hw0 + wave;

  // ---- A-frags of X for this wave's site (non-temporal, 16B aligned) ----
  bf16x8 ax[8];
  {
    const unsigned short* xs = xT + (((size_t)(b * 1024 + site)) << 12) + lrow * 256;
#pragma unroll
    for (int ks = 0; ks < 8; ++ks) ax[ks] = ntload8(xs + ks * 32 + quad * 8);
  }

  unsigned short* qb = smem + kWB + wave * kSite;
  unsigned short* kb = qb + 640;
  unsigned short* vt = qb + 1280;  // vT[d][j], stride 16

  const int stageDst = (tid >> 4) * kWBStride + (tid & 15) * 16;
  const int stageSrcOff = (tid >> 4) * 256 + (tid & 15) * 16;

  uint4 pr0, pr1;  // prefetch tile 0
  {
    const unsigned short* sp = wAll + stageSrcOff;
    pr0 = *(const uint4*)sp;
    pr1 = *(const uint4*)(sp + 8);
  }

  const f32x4 zero4 = {0.f, 0.f, 0.f, 0.f};
  const float scale = 0.17677669529663687f;  // 32^-0.5
  bf16x8 ao[8];

  // stage tile g (dbuf) + prefetch g+1, then 16x 16x16x32 MFMA (2 acc chains)
  auto qkv_tile = [&](int g, float bias0, float bias1) -> Acc2 {
    __syncthreads();  // WB[g&1] free
    unsigned short* WBc = smem + (g & 1) * kWBTile;
    *(uint4*)(WBc + stageDst) = pr0;
    *(uint4*)(WBc + stageDst + 8) = pr1;
    {
      const unsigned short* sp = wAll + (size_t)(g + 1) * 32 * 256 + stageSrcOff;
      pr0 = *(const uint4*)sp;
      pr1 = *(const uint4*)(sp + 8);
    }
    __syncthreads();  // WB[g&1] ready
    Acc2 acc;
    acc.a0 = f32x4{bias0, bias0, bias0, bias0};
    acc.a1 = f32x4{bias1, bias1, bias1, bias1};
    const unsigned short* br0 = WBc + lrow * kWBStride + quad * 8;
    const unsigned short* br1 = WBc + (16 + lrow) * kWBStride + quad * 8;
#pragma unroll
    for (int ks = 0; ks < 8; ++ks) {
      const bf16x8 b0 = *(const bf16x8*)(br0 + ks * 32);
      const bf16x8 b1 = *(const bf16x8*)(br1 + ks * 32);
      acc.a0 = __builtin_amdgcn_mfma_f32_16x16x32_bf16(ax[ks], b0, acc.a0, 0, 0, 0);
      acc.a1 = __builtin_amdgcn_mfma_f32_16x16x32_bf16(ax[ks], b1, acc.a1, 0, 0, 0);
    }
    return acc;
  };

#pragma unroll 1
  for (int h = 0; h < 8; ++h) {
    const Acc2 qa = qkv_tile(h * 3 + 0, bqkv[h * 32 + lrow], bqkv[h * 32 + 16 + lrow]);
    const Acc2 ka = qkv_tile(h * 3 + 1, bqkv[256 + h * 32 + lrow], bqkv[256 + h * 32 + 16 + lrow]);
    const Acc2 va = qkv_tile(h * 3 + 2, bqkv[512 + h * 32 + lrow], bqkv[512 + h * 32 + 16 + lrow]);
    float rl[4];
#pragma unroll
    for (int r = 0; r < 4; ++r) rl[r] = rel[h * 256 + (quad * 4 + r) * 16 + lrow];

    // ---- site bufs (wave-private): q,k [t][d] s40; vT [d][j] s16 ----
#pragma unroll
    for (int r = 0; r < 4; ++r) {
      const int row = quad * 4 + r;
      qb[row * 40 + lrow] = f2bf(qa.a0[r]);
      qb[row * 40 + 16 + lrow] = f2bf(qa.a1[r]);
      kb[row * 40 + lrow] = f2bf(ka.a0[r]);
      kb[row * 40 + 16 + lrow] = f2bf(ka.a1[r]);
    }
    {  // vT: j = quad*4+r consecutive -> uint2 writes
      uint2 w0, w1;
      w0.x = pack2(va.a0[0], va.a0[1]);
      w0.y = pack2(va.a0[2], va.a0[3]);
      w1.x = pack2(va.a1[0], va.a1[1]);
      w1.y = pack2(va.a1[2], va.a1[3]);
      *(uint2*)&vt[lrow * 16 + quad * 4] = w0;
      *(uint2*)&vt[(16 + lrow) * 16 + quad * 4] = w1;
    }

    // ---- sim + softmax ----
    const bf16x8 qf = *(const bf16x8*)(qb + lrow * 40 + quad * 8);
    const bf16x8 kf = *(const bf16x8*)(kb + lrow * 40 + quad * 8);
    const f32x4 sim = __builtin_amdgcn_mfma_f32_16x16x32_bf16(qf, kf, zero4, 0, 0, 0);
    float p[4], inv[4];
#pragma unroll
    for (int r = 0; r < 4; ++r) {
      const float v = sim[r] * scale + rl[r];
      float m = v;
      for (int off = 8; off; off >>= 1) m = fmaxf(m, __shfl_xor(m, off));
      const float e = __expf(v - m);
      float sum = e;
      for (int off = 8; off; off >>= 1) sum += __shfl_xor(sum, off);
      p[r] = e;
      inv[r] = 1.0f / sum;
    }
    unsigned short* pb = kb;  // P overlays k (dead), stride 24
#pragma unroll
    for (int r = 0; r < 4; ++r) pb[(quad * 4 + r) * 24 + lrow] = f2bf(p[r]);

    // ---- P@V ----
    bf16x8 pf, vf0, vf1;
    if (quad < 2) {
      pf = *(const bf16x8*)(pb + lrow * 24 + quad * 8);
      vf0 = *(const bf16x8*)(vt + lrow * 16 + quad * 8);
      vf1 = *(const bf16x8*)(vt + (16 + lrow) * 16 + quad * 8);
    } else {
#pragma unroll
      for (int j = 0; j < 8; ++j) { pf[j] = 0; vf0[j] = 0; vf1[j] = 0; }
    }
    const f32x4 o0 = __builtin_amdgcn_mfma_f32_16x16x32_bf16(pf, vf0, zero4, 0, 0, 0);
    const f32x4 o1 = __builtin_amdgcn_mfma_f32_16x16x32_bf16(pf, vf1, zero4, 0, 0, 0);
#pragma unroll
    for (int r = 0; r < 4; ++r) {  // O bounce into qb (dead) -> A-layout
      const int t = quad * 4 + r;
      qb[t * 40 + lrow] = f2bf(o0[r] * inv[r]);
      qb[t * 40 + 16 + lrow] = f2bf(o1[r] * inv[r]);
    }
    ao[h] = *(const bf16x8*)(qb + lrow * 40 + quad * 8);
  }  // head loop

  // ---- epilogue: y = O @ wout^T + bout; coalesced NT stores via fp32 LDS ----
  __syncthreads();
  float* fbuf = (float*)smem;  // [(t*32 + c_l)] * 9 + hw_l   (512 lines x 9)
  float* ob = out + ((size_t)b << 22);
#pragma unroll 1
  for (int cc = 0; cc < 8; ++cc) {
#pragma unroll
    for (int sub = 0; sub < 2; ++sub) {
      const int c = cc * 32 + sub * 16 + lrow;
      const float bias = bout[c];
      f32x4 y = {bias, bias, bias, bias};
#pragma unroll
      for (int ks = 0; ks < 8; ++ks) {
        const bf16x8 wf =
            *(const bf16x8*)(wAll + (size_t)(768 + c) * 256 + ks * 32 + quad * 8);
        y = __builtin_amdgcn_mfma_f32_16x16x32_bf16(ao[ks], wf, y, 0, 0, 0);
      }
#pragma unroll
      for (int r = 0; r < 4; ++r) {
        const int t = quad * 4 + r;
        fbuf[(t * 32 + sub * 16 + lrow) * 9 + wave] = y[r];
      }
    }
    __syncthreads();
    {
      const int t = tid >> 5, cl = tid & 31;
      float v[8];
#pragma unroll
      for (int i = 0; i < 8; ++i) v[i] = fbuf[tid * 9 + i];
      float* dst = ob + ((size_t)(t * 256 + cc * 32 + cl)) * 1024 + hw0;
      f32x4 q0, q1;
      q0.x = v[0]; q0.y = v[1]; q0.z = v[2]; q0.w = v[3];
      q1.x = v[4]; q1.y = v[5]; q1.z = v[6]; q1.w = v[7];
      __builtin_nontemporal_store(q0, (f32x4*)dst);
      __builtin_nontemporal_store(q1, (f32x4*)(dst + 4));
    }
    __syncthreads();
  }
}

// ============================ fallback (round-2, passed) ============================
constexpr int kHWT = 4;
constexpr int kXsTStride = kC * kHWT + 8;
constexpr int kXSize = kT * kXsTStride;
constexpr int kWsOff = kXSize;
constexpr int kWsStride = 264;
constexpr int kWsSize = 32 * kWsStride;
constexpr int kQbOff = kWsOff + kWsSize;
constexpr int kQbWave = 1792;
constexpr int kLdsElems = kQbOff + 4 * kQbWave;

__global__ __launch_bounds__(256, 2) void fused_temporal_attn(
    const float* __restrict__ x, const float* __restrict__ rel,
    const float* __restrict__ wqkv, const float* __restrict__ bqkv,
    const float* __restrict__ wout, const float* __restrict__ bout,
    float* __restrict__ out) {
  __shared__ __align__(16) unsigned short smem[kLdsElems];
  const int tid = threadIdx.x;
  const int lane = tid & 63;
  const int wave = tid >> 6;
  const int quad = lane >> 4;
  const int lrow = lane & 15;
  const int b = blockIdx.x >> 8;
  const int tile = blockIdx.x & 255;
  const int hw0 = tile * kHWT;
  {
    const float* xb = x + (size_t)b * kT * kC * kHW + hw0;
#pragma unroll
    for (int it = 0; it < 16; ++it) {
      int idx = it * 256 + tid;
      int t = idx >> 8, c = idx & 255;
      const float4 v = *(const float4*)(xb + (size_t)(t * kC + c) * kHW);
      uint2 p;
      p.x = pack2(v.x, v.y);
      p.y = pack2(v.z, v.w);
      *(uint2*)&smem[t * kXsTStride + c * kHWT] = p;
    }
  }
  __syncthreads();
  bf16x8 ax[8];
#pragma unroll
  for (int ks = 0; ks < 8; ++ks) {
    bf16x8 f;
#pragma unroll
    for (int j = 0; j < 8; ++j) {
      int c = ks * 32 + quad * 8 + j;
      f[j] = (short)smem[lrow * kXsTStride + c * kHWT + wave];
    }
    ax[ks] = f;
  }
  unsigned short* qb = &smem[kQbOff + wave * kQbWave];
  unsigned short* kbuf = qb + 512;
  unsigned short* vtb = qb + 1024;
  unsigned short* pb = qb + 1536;
  const f32x4 zero4 = {0.f, 0.f, 0.f, 0.f};
  bf16x8 ao[8];
  for (int head = 0; head < 8; ++head) {
    for (int sel = 0; sel < 3; ++sel) {
      __syncthreads();
      {
        const float* wbp = wqkv + (size_t)(sel * 256 + head * 32) * kC;
#pragma unroll
        for (int i = 0; i < 8; ++i) {
          int seg = i * 256 + tid;
          int d = seg >> 6, s = seg & 63;
          const float4 v = *(const float4*)(wbp + d * kC + s * 4);
          uint2 p;
          p.x = pack2(v.x, v.y);
          p.y = pack2(v.z, v.w);
          *(uint2*)&smem[kWsOff + d * kWsStride + s * 4] = p;
        }
      }
      __syncthreads();
      float bias0 = bqkv[sel * 256 + head * 32 + lrow];
      float bias1 = bqkv[sel * 256 + head * 32 + 16 + lrow];
      f32x4 acc0 = {bias0, bias0, bias0, bias0};
      f32x4 acc1 = {bias1, bias1, bias1, bias1};
#pragma unroll
      for (int ks = 0; ks < 8; ++ks) {
        bf16x8 b0 = *(const bf16x8*)&smem[kWsOff + lrow * kWsStride + ks * 32 + quad * 8];
        bf16x8 b1 = *(const bf16x8*)&smem[kWsOff + (16 + lrow) * kWsStride + ks * 32 + quad * 8];
        acc0 = __builtin_amdgcn_mfma_f32_16x16x32_bf16(ax[ks], b0, acc0, 0, 0, 0);
        acc1 = __builtin_amdgcn_mfma_f32_16x16x32_bf16(ax[ks], b1, acc1, 0, 0, 0);
      }
      if (sel < 2) {
        unsigned short* dst = sel ? kbuf : qb;
#pragma unroll
        for (int r = 0; r < 4; ++r) {
          int row = quad * 4 + r;
          dst[row * 32 + lrow] = f2bf(acc0[r]);
          dst[row * 32 + 16 + lrow] = f2bf(acc1[r]);
        }
      } else {
#pragma unroll
        for (int r = 0; r < 4; ++r) {
          int row = quad * 4 + r;
          vtb[lrow * 16 + row] = f2bf(acc0[r]);
          vtb[(16 + lrow) * 16 + row] = f2bf(acc1[r]);
        }
      }
    }
    bf16x8 qf = *(const bf16x8*)&qb[lrow * 32 + quad * 8];
    bf16x8 kf = *(const bf16x8*)&kbuf[lrow * 32 + quad * 8];
    f32x4 sim = __builtin_amdgcn_mfma_f32_16x16x32_bf16(qf, kf, zero4, 0, 0, 0);
    const float scale = 0.17677669529663687f;
    float p[4], rsum[4];
#pragma unroll
    for (int r = 0; r < 4; ++r) {
      int i = quad * 4 + r;
      float v = sim[r] * scale + rel[head * 256 + i * 16 + lrow];
      float m = v;
      for (int off = 8; off; off >>= 1) m = fmaxf(m, __shfl_xor(m, off));
      float e = __expf(v - m);
      float s = e;
      for (int off = 8; off; off >>= 1) s += __shfl_xor(s, off);
      p[r] = e;
      rsum[r] = s;
    }
#pragma unroll
    for (int r = 0; r < 4; ++r) pb[(quad * 4 + r) * 16 + lrow] = f2bf(p[r]);
    bf16x8 pf, vf0, vf1;
    if (quad < 2) {
      pf = *(const bf16x8*)&pb[lrow * 16 + quad * 8];
      vf0 = *(const bf16x8*)&vtb[lrow * 16 + quad * 8];
      vf1 = *(const bf16x8*)&vtb[(16 + lrow) * 16 + quad * 8];
    } else {
#pragma unroll
      for (int j = 0; j < 8; ++j) { pf[j] = 0; vf0[j] = 0; vf1[j] = 0; }
    }
    f32x4 o0 = __builtin_amdgcn_mfma_f32_16x16x32_bf16(pf, vf0, zero4, 0, 0, 0);
    f32x4 o1 = __builtin_amdgcn_mfma_f32_16x16x32_bf16(pf, vf1, zero4, 0, 0, 0);
#pragma unroll
    for (int r = 0; r < 4; ++r) {
      int t = quad * 4 + r;
      float inv = 1.0f / rsum[r];
      qb[t * 32 + lrow] = f2bf(o0[r] * inv);
      qb[t * 32 + 16 + lrow] = f2bf(o1[r] * inv);
    }
    ao[head] = *(const bf16x8*)&qb[lrow * 32 + quad * 8];
  }
  float* ob = out + (size_t)b * kT * kC * kHW + hw0 + wave;
#pragma unroll 1
  for (int nt = 0; nt < 16; ++nt) {
    int c = nt * 16 + lrow;
    float bias = bout[c];
    f32x4 y = {bias, bias, bias, bias};
#pragma unroll
    for (int ks = 0; ks < 8; ++ks) {
      const float4 w0 = *(const float4*)(wout + (size_t)c * kC + ks * 32 + quad * 8);
      const float4 w1 = *(const float4*)(wout + (size_t)c * kC + ks * 32 + quad * 8 + 4);
      bf16x8 wf;
      wf[0] = (short)f2bf(w0.x); wf[1] = (short)f2bf(w0.y);
      wf[2] = (short)f2bf(w0.z); wf[3] = (short)f2bf(w0.w);
      wf[4] = (short)f2bf(w1.x); wf[5] = (short)f2bf(w1.y);
      wf[6] = (short)f2bf(w1.z); wf[7] = (short)f2bf(w1.w);
      y = __builtin_amdgcn_mfma_f32_16x16x32_bf16(ao[ks], wf, y, 0, 0, 0);
    }
#pragma unroll
    for (int r = 0; r < 4; ++r) {
      int t = quad * 4 + r;
      ob[(size_t)(t * kC + c) * kHW] = y[r];
    }
  }
}

}  // namespace

extern "C" void kernel_launch(void* const* d_in, const int* in_sizes, int n_in,
                              void* d_out, int out_size, void* d_ws, size_t ws_size,
                              hipStream_t stream) {
  const float* x = (const float*)d_in[0];
  const float* rel = (const float*)d_in[1];
  const float* wqkv = (const float*)d_in[2];
  const float* bqkv = (const float*)d_in[3];
  const float* wout = (const float*)d_in[4];
  const float* bout = (const float*)d_in[5];
  float* out = (float*)d_out;
  (void)in_sizes; (void)n_in; (void)out_size;

  constexpr size_t kXTElems = (size_t)4 * 1024 * 16 * 256;  // 16,777,216
  constexpr size_t kWAllElems = 1024 * 256;                 // 262,144
  constexpr size_t kNeed = (kXTElems + kWAllElems) * sizeof(unsigned short);

  if (ws_size >= kNeed) {
    unsigned short* xT = (unsigned short*)d_ws;
    unsigned short* wAll = xT + kXTElems;
    prep<<<4096 + 32, 256, 0, stream>>>(x, wqkv, wout, xT, wAll);
    attn_main<<<512, 512, 0, stream>>>(xT, rel, wAll, bqkv, bout, out);
  } else {
    fused_temporal_attn<<<1024, 256, 0, stream>>>(x, rel, wqkv, bqkv, wout, bout, out);
  }
}